// Round 4
// baseline (683.693 us; speedup 1.0000x reference)
//
#include <hip/hip_runtime.h>
#include <hip/hip_fp16.h>
#include <cstdint>
#include <cstddef>
#include <cmath>

// Problem constants
#define T_TOK 16384      // B*S tokens
#define DIN   2048
#define HIDN  256
#define NHEAD 16
#define HDIM  128
#define NKT   32         // DIN / 64
#define CAPH  4608       // per-head token capacity (mean 4096, sd ~55 -> 9 sigma)

typedef __attribute__((ext_vector_type(4))) float    f32x4;
typedef __attribute__((ext_vector_type(4))) int      i32x4;
typedef __attribute__((ext_vector_type(8))) _Float16 f16x8;
typedef __attribute__((ext_vector_type(4))) _Float16 f16x4;

// ---- workspace layout (bytes) ----
#define OFF_XH   ((size_t)0)
#define OFF_XL   ((size_t)67108864)
#define OFF_WH   ((size_t)134217728)
#define OFF_RWH  ((size_t)142606336)
#define OFF_RWL  ((size_t)143654912)
#define OFF_CN   ((size_t)144703488)
// bucketing scratch reuses the xl region (xl is dead after router_kernel):
#define OFF_CNT  (OFF_XL)                 // 16 ints
#define OFF_PERM (OFF_XL + 1024)          // 16*4608 ints  (token<<2 | slot)
#define OFF_PR   (OFF_PERM + (size_t)NHEAD * CAPH * 4)   // 16*4608 floats
// z scratch lives in d_out (16.7 MB of 33.5 MB); main_sparse fully overwrites d_out later.

__device__ __forceinline__ void gl_lds16(const void* g, void* l) {
  __builtin_amdgcn_global_load_lds(
      (const __attribute__((address_space(1))) unsigned int*)g,
      (__attribute__((address_space(3))) unsigned int*)l, 16, 0, 0);
}

// ---------------- prep: fp32 -> tiled fp16 (hi/lo split) ----------------
__global__ void prep_convert(const float* __restrict__ x,
                             const float* __restrict__ w,
                             const float* __restrict__ rw,
                             _Float16* __restrict__ xh, _Float16* __restrict__ xl,
                             _Float16* __restrict__ wh,
                             _Float16* __restrict__ rwh, _Float16* __restrict__ rwl) {
  size_t i = (size_t)blockIdx.x * 256 + threadIdx.x;
  if (i < 8388608) {                       // x: 16384 x 2048 (float4 units)
    const f32x4 v = ((const f32x4*)x)[i];
    size_t t = i >> 9;
    int r4 = (int)(i & 511);
    int kt = r4 >> 4;
    int k  = (r4 & 15) << 2;
    size_t o = (((size_t)kt * T_TOK + t) << 6) + k;
    _Float16 h0 = (_Float16)v.x, h1 = (_Float16)v.y,
             h2 = (_Float16)v.z, h3 = (_Float16)v.w;
    *(f16x4*)(xh + o) = (f16x4){h0, h1, h2, h3};
    _Float16 l0 = (_Float16)((v.x - (float)h0) * 4096.0f);
    _Float16 l1 = (_Float16)((v.y - (float)h1) * 4096.0f);
    _Float16 l2 = (_Float16)((v.z - (float)h2) * 4096.0f);
    _Float16 l3 = (_Float16)((v.w - (float)h3) * 4096.0f);
    *(f16x4*)(xl + o) = (f16x4){l0, l1, l2, l3};
  } else if (i < 9437184) {                // weight: 2048 x 2048, scaled x64
    size_t j = i - 8388608;
    const f32x4 v = ((const f32x4*)w)[j];
    size_t row = j >> 9;
    int r4 = (int)(j & 511);
    int kt = r4 >> 4;
    int k  = (r4 & 15) << 2;
    size_t o = (((size_t)kt * 2048 + row) << 6) + k;
    *(f16x4*)(wh + o) = (f16x4){(_Float16)(v.x * 64.0f), (_Float16)(v.y * 64.0f),
                                (_Float16)(v.z * 64.0f), (_Float16)(v.w * 64.0f)};
  } else if (i < 9568256) {                // router_w: 256 x 2048, hi/lo
    size_t j = i - 9437184;
    const f32x4 v = ((const f32x4*)rw)[j];
    size_t row = j >> 9;
    int r4 = (int)(j & 511);
    int kt = r4 >> 4;
    int k  = (r4 & 15) << 2;
    size_t o = (((size_t)kt * 256 + row) << 6) + k;
    _Float16 h0 = (_Float16)v.x, h1 = (_Float16)v.y,
             h2 = (_Float16)v.z, h3 = (_Float16)v.w;
    *(f16x4*)(rwh + o) = (f16x4){h0, h1, h2, h3};
    _Float16 l0 = (_Float16)((v.x - (float)h0) * 4096.0f);
    _Float16 l1 = (_Float16)((v.y - (float)h1) * 4096.0f);
    _Float16 l2 = (_Float16)((v.z - (float)h2) * 4096.0f);
    _Float16 l3 = (_Float16)((v.w - (float)h3) * 4096.0f);
    *(f16x4*)(rwl + o) = (f16x4){l0, l1, l2, l3};
  }
}

// ---------------- centroid normalize (fp64 norm, fp32 division like np) ----------------
__global__ void prep_cnorm(const float* __restrict__ c, float* __restrict__ cn) {
  int tid = threadIdx.x;              // 256 threads
  int h = tid >> 4, j = tid & 15;
  double s = 0.0;
  #pragma unroll
  for (int q = 0; q < 16; q++) {
    double v = (double)c[h * HIDN + j * 16 + q];
    s = fma(v, v, s);
  }
  s += __shfl_xor(s, 1, 64);
  s += __shfl_xor(s, 2, 64);
  s += __shfl_xor(s, 4, 64);
  s += __shfl_xor(s, 8, 64);
  float nf = (float)fmax(sqrt(s), 1e-12);
  #pragma unroll
  for (int q = 0; q < 16; q++)
    cn[h * HIDN + j * 16 + q] = c[h * HIDN + j * 16 + q] / nf;
}

// ---------------- router z-GEMM: N-split 128 cols, single staging phase, 2 barriers/kt ----
// Arithmetic chain per output element identical to R2/R3 (bit-frozen):
//   accA: hi*hi ks0, ks1 -> zacc(fp64) per kt; accB: lo*hi(ks0,ks1) then hi*lo(ks0,ks1).
__launch_bounds__(512, 2)
__global__ void router_kernel(const _Float16* __restrict__ xh,
                              const _Float16* __restrict__ xl,
                              const _Float16* __restrict__ rwh,
                              const _Float16* __restrict__ rwl,
                              float* __restrict__ zf) {
  __shared__ struct {
    _Float16 Ah[64 * 64];    // 8 KB
    _Float16 Al[64 * 64];    // 8 KB
    _Float16 Bh[128 * 64];   // 16 KB
    _Float16 Bl[128 * 64];   // 16 KB
  } u;                       // 48 KB

  const int tid  = threadIdx.x;
  const int w    = tid >> 6;
  const int lane = tid & 63;
  const int lm   = lane & 15;
  const int quad = lane >> 4;
  const int wm   = w & 1;    // m-half (32 rows)
  const int wn   = w >> 1;   // n-quarter of 128 (32 cols)
  const int t0   = blockIdx.x * 64;
  const int nb   = blockIdx.y;          // 0/1: which 128-col half of HIDN

  double zacc[2][2][4];
  f32x4 accB[2][2];
  #pragma unroll
  for (int a = 0; a < 2; a++)
    #pragma unroll
    for (int b = 0; b < 2; b++) {
      accB[a][b] = (f32x4)0.0f;
      #pragma unroll
      for (int q = 0; q < 4; q++) zacc[a][b][q] = 0.0;
    }

  for (int kt = 0; kt < NKT; kt++) {
    if (kt) __syncthreads();
    {
      const char* ah_src = (const char*)(xh + (((size_t)kt * T_TOK + t0) << 6));
      const char* al_src = (const char*)(xl + (((size_t)kt * T_TOK + t0) << 6));
      const char* bh_src = (const char*)(rwh + (((size_t)kt * 256 + nb * 128) << 6));
      const char* bl_src = (const char*)(rwl + (((size_t)kt * 256 + nb * 128) << 6));
      gl_lds16(ah_src + w * 1024 + lane * 16, (char*)u.Ah + w * 1024);
      gl_lds16(al_src + w * 1024 + lane * 16, (char*)u.Al + w * 1024);
      #pragma unroll
      for (int c = 0; c < 2; c++) {
        gl_lds16(bh_src + (w * 2 + c) * 1024 + lane * 16, (char*)u.Bh + (w * 2 + c) * 1024);
        gl_lds16(bl_src + (w * 2 + c) * 1024 + lane * 16, (char*)u.Bl + (w * 2 + c) * 1024);
      }
    }
    __syncthreads();
    f32x4 accA[2][2];
    #pragma unroll
    for (int a = 0; a < 2; a++)
      #pragma unroll
      for (int b = 0; b < 2; b++) accA[a][b] = (f32x4)0.0f;
    // phase 1: accA += Ah*Bh ; accB += Al*Bh  (ks0 then ks1)
    #pragma unroll
    for (int ks = 0; ks < 2; ks++) {
      const int ko = ks * 32 + quad * 8;
      f16x8 ah[2], al[2], bh[2];
      #pragma unroll
      for (int fm = 0; fm < 2; fm++) {
        int r = wm * 32 + fm * 16 + lm;
        ah[fm] = *(const f16x8*)(u.Ah + r * 64 + ko);
        al[fm] = *(const f16x8*)(u.Al + r * 64 + ko);
      }
      #pragma unroll
      for (int fn = 0; fn < 2; fn++) {
        int r = wn * 32 + fn * 16 + lm;
        bh[fn] = *(const f16x8*)(u.Bh + r * 64 + ko);
      }
      #pragma unroll
      for (int fm = 0; fm < 2; fm++)
        #pragma unroll
        for (int fn = 0; fn < 2; fn++) {
          accA[fm][fn] = __builtin_amdgcn_mfma_f32_16x16x32_f16(ah[fm], bh[fn], accA[fm][fn], 0, 0, 0);
          accB[fm][fn] = __builtin_amdgcn_mfma_f32_16x16x32_f16(al[fm], bh[fn], accB[fm][fn], 0, 0, 0);
        }
    }
    // phase 2: accB += Ah*Bl  (ks0 then ks1) -- Bl already staged, no barrier
    #pragma unroll
    for (int ks = 0; ks < 2; ks++) {
      const int ko = ks * 32 + quad * 8;
      f16x8 ah[2], bl[2];
      #pragma unroll
      for (int fm = 0; fm < 2; fm++) {
        int r = wm * 32 + fm * 16 + lm;
        ah[fm] = *(const f16x8*)(u.Ah + r * 64 + ko);
      }
      #pragma unroll
      for (int fn = 0; fn < 2; fn++) {
        int r = wn * 32 + fn * 16 + lm;
        bl[fn] = *(const f16x8*)(u.Bl + r * 64 + ko);
      }
      #pragma unroll
      for (int fm = 0; fm < 2; fm++)
        #pragma unroll
        for (int fn = 0; fn < 2; fn++)
          accB[fm][fn] = __builtin_amdgcn_mfma_f32_16x16x32_f16(ah[fm], bl[fn], accB[fm][fn], 0, 0, 0);
    }
    // fp64 outer accumulation of this K-tile's hi*hi partial
    #pragma unroll
    for (int fm = 0; fm < 2; fm++)
      #pragma unroll
      for (int fn = 0; fn < 2; fn++)
        #pragma unroll
        for (int q = 0; q < 4; q++)
          zacc[fm][fn][q] += (double)accA[fm][fn][q];
  }

  // epilogue: identical arithmetic, direct global store
  #pragma unroll
  for (int fm = 0; fm < 2; fm++)
    #pragma unroll
    for (int fn = 0; fn < 2; fn++)
      #pragma unroll
      for (int i2 = 0; i2 < 4; i2++) {
        const int row = t0 + wm * 32 + fm * 16 + quad * 4 + i2;
        const int col = nb * 128 + wn * 32 + fn * 16 + lm;
        zf[(size_t)row * 256 + col] =
            (float)(zacc[fm][fn][i2] + (double)accB[fm][fn][i2] * (1.0 / 4096.0));
      }
}

// ---------------- zero head counters (runs after router frees the xl region) ----------------
__global__ void zero_cnt(int* __restrict__ cnt) {
  if (threadIdx.x < NHEAD) cnt[threadIdx.x] = 0;
}

// ---------------- routing: l2norm, logits, softmax, top-4 (bit-exact) + bucket scatter ----
__launch_bounds__(256, 4)
__global__ void route_topk(const float* __restrict__ zf,
                           const float* __restrict__ cn,
                           const float* __restrict__ temp,
                           int* __restrict__ cnt,
                           int* __restrict__ perm,
                           float* __restrict__ pr) {
  const int tid  = threadIdx.x;
  const int w    = tid >> 6;
  const int lane = tid & 63;
  const int lm   = lane & 15;
  const int quad = lane >> 4;
  const int t    = blockIdx.x * 16 + w * 4 + quad;

  const float* zrow = zf + (size_t)t * 256;
  double ssq = 0.0;
  #pragma unroll
  for (int c16 = 0; c16 < 16; c16++) {
    double zv = (double)zrow[c16 * 16 + lm];
    ssq = fma(zv, zv, ssq);
  }
  ssq += __shfl_xor(ssq, 1, 64);
  ssq += __shfl_xor(ssq, 2, 64);
  ssq += __shfl_xor(ssq, 4, 64);
  ssq += __shfl_xor(ssq, 8, 64);
  const float* crow = cn + lm * 256;
  double dot = 0.0;
  #pragma unroll 8
  for (int c = 0; c < 256; c++)
    dot = fma((double)zrow[c], (double)crow[c], dot);
  double nd = fmax(sqrt(ssq), 1e-12);
  float lgt = (float)(dot / nd) * 0.0625f * expf(temp[0]);

  float mx = lgt;
  mx = fmaxf(mx, __shfl_xor(mx, 1, 64));
  mx = fmaxf(mx, __shfl_xor(mx, 2, 64));
  mx = fmaxf(mx, __shfl_xor(mx, 4, 64));
  mx = fmaxf(mx, __shfl_xor(mx, 8, 64));
  float e = (float)exp((double)(lgt - mx));
  float s = e;
  s = s + __shfl_xor(s, 8, 64);
  s = s + __shfl_xor(s, 1, 64);
  s = s + __shfl_xor(s, 2, 64);
  s = s + __shfl_xor(s, 4, 64);
  float p = e / s;      // IEEE fp32 division

  // top-4: lexicographic max on (p, -h) == serial strict-> scan, lowest-index ties
  float pc = p;
  int bi[4]; float bp[4];
  #pragma unroll
  for (int k = 0; k < 4; k++) {
    float bv = pc; int bh = lm;
    #pragma unroll
    for (int m = 1; m < 16; m <<= 1) {
      float ov = __shfl_xor(bv, m, 64);
      int   oh = __shfl_xor(bh, m, 64);
      bool take = (ov > bv) || (ov == bv && oh < bh);
      bv = take ? ov : bv;
      bh = take ? oh : bh;
    }
    bi[k] = bh; bp[k] = bv;
    if (lm == bh) pc = -1.0f;
  }
  if (lm == 0) {
    #pragma unroll
    for (int k = 0; k < 4; k++) {
      int hs = bi[k];
      int pos = atomicAdd(&cnt[hs], 1);
      if (pos < CAPH) {
        perm[hs * CAPH + pos] = (t << 2) | k;
        pr[hs * CAPH + pos]   = bp[k];
      }
    }
  }
}

// ---------------- sparse main GEMM: per-head gathered tokens, 4x fewer FLOPs ----------------
// MFMA chain per (token, head) output element identical to the dense R3 kernel (bit-frozen).
__launch_bounds__(256, 4)
__global__ void main_sparse(const _Float16* __restrict__ xh,
                            const _Float16* __restrict__ wh,
                            const float* __restrict__ bias,
                            const int* __restrict__ cnt,
                            const int* __restrict__ perm,
                            const float* __restrict__ pr,
                            float* __restrict__ out) {
  __shared__ _Float16 As[128 * 64];
  __shared__ _Float16 Bs[128 * 64];
  __shared__ int   tokS[128];
  __shared__ int   slotS[128];
  __shared__ float prbS[128];
  __shared__ int   vldS[128];

  const int tid  = threadIdx.x;
  const int w    = tid >> 6;
  const int lane = tid & 63;
  const int lm   = lane & 15;
  const int quad = lane >> 4;
  const int wm   = w & 1;
  const int wn   = w >> 1;
  const int h    = blockIdx.y;

  const int cnt_h = min(cnt[h], CAPH);
  const int base  = blockIdx.x * 128;
  if (base >= cnt_h) return;
  const int rows = min(128, cnt_h - base);

  if (tid < 128) {
    int idx = h * CAPH + base + (tid < rows ? tid : 0);
    int e = perm[idx];
    tokS[tid]  = e >> 2;
    slotS[tid] = e & 3;
    prbS[tid]  = pr[idx];
    vldS[tid]  = (tid < rows) ? 1 : 0;
  }
  __syncthreads();

  // per-lane gathered row tokens for the 4 A-staging calls
  int tokc[4];
  #pragma unroll
  for (int c = 0; c < 4; c++)
    tokc[c] = tokS[w * 32 + c * 8 + (lane >> 3)];

  f32x4 acc[4][4];
  #pragma unroll
  for (int a = 0; a < 4; a++)
    #pragma unroll
    for (int b = 0; b < 4; b++) acc[a][b] = (f32x4)0.0f;

  const char* xh_b = (const char*)xh;
  for (int kt = 0; kt < NKT; kt++) {
    if (kt) __syncthreads();
    const char* bsrc = (const char*)(wh + (((size_t)kt * 2048 + h * 128) << 6));
    #pragma unroll
    for (int c = 0; c < 4; c++) {
      // A: gather row tokc[c]; 8 lanes per 128B row
      gl_lds16(xh_b + (((size_t)kt * T_TOK + tokc[c]) << 7) + (lane & 7) * 16,
               (char*)As + (w * 4 + c) * 1024);
      gl_lds16(bsrc + (w * 4 + c) * 1024 + lane * 16, (char*)Bs + (w * 4 + c) * 1024);
    }
    __syncthreads();
    #pragma unroll
    for (int ks = 0; ks < 2; ks++) {
      const int ko = ks * 32 + quad * 8;
      f16x8 a[4], b[4];
      #pragma unroll
      for (int f = 0; f < 4; f++)
        a[f] = *(const f16x8*)(As + (wm * 64 + f * 16 + lm) * 64 + ko);
      #pragma unroll
      for (int f = 0; f < 4; f++)
        b[f] = *(const f16x8*)(Bs + (wn * 64 + f * 16 + lm) * 64 + ko);
      #pragma unroll
      for (int fm = 0; fm < 4; fm++)
        #pragma unroll
        for (int fn = 0; fn < 4; fn++)
          acc[fm][fn] = __builtin_amdgcn_mfma_f32_16x16x32_f16(a[fm], b[fn], acc[fm][fn], 0, 0, 0);
    }
  }

  float bias_v[4];
  #pragma unroll
  for (int fn = 0; fn < 4; fn++)
    bias_v[fn] = bias[h * 128 + wn * 64 + fn * 16 + lm];

  #pragma unroll
  for (int fm = 0; fm < 4; fm++) {
    const int rbase = wm * 64 + fm * 16 + quad * 4;
    #pragma unroll
    for (int i2 = 0; i2 < 4; i2++) {
      const int rr = rbase + i2;
      if (vldS[rr]) {
        const float sc = prbS[rr];
        const size_t obase = (size_t)tokS[rr] * 512 + (size_t)slotS[rr] * 128 + wn * 64;
        #pragma unroll
        for (int fn = 0; fn < 4; fn++)
          out[obase + fn * 16 + lm] = (acc[fm][fn][i2] * (1.0f / 64.0f) + bias_v[fn]) * sc;
      }
    }
  }
}

extern "C" void kernel_launch(void* const* d_in, const int* in_sizes, int n_in,
                              void* d_out, int out_size, void* d_ws, size_t ws_size,
                              hipStream_t stream) {
  const float* x    = (const float*)d_in[0];
  const float* rw   = (const float*)d_in[1];
  const float* hc   = (const float*)d_in[2];
  const float* temp = (const float*)d_in[3];
  const float* wt   = (const float*)d_in[4];
  const float* bias = (const float*)d_in[5];
  float* out = (float*)d_out;
  char* ws = (char*)d_ws;

  _Float16* xh   = (_Float16*)(ws + OFF_XH);
  _Float16* xl   = (_Float16*)(ws + OFF_XL);
  _Float16* wh   = (_Float16*)(ws + OFF_WH);
  _Float16* rwh  = (_Float16*)(ws + OFF_RWH);
  _Float16* rwl  = (_Float16*)(ws + OFF_RWL);
  float*    cn   = (float*)(ws + OFF_CN);
  int*      cnt  = (int*)(ws + OFF_CNT);    // aliases xl (dead after router)
  int*      perm = (int*)(ws + OFF_PERM);
  float*    pr   = (float*)(ws + OFF_PR);
  float*    zf   = out;   // 16.7 MB scratch inside d_out; fully overwritten by main_sparse

  hipLaunchKernelGGL(prep_convert, dim3(37376), dim3(256), 0, stream,
                     x, wt, rw, xh, xl, wh, rwh, rwl);
  hipLaunchKernelGGL(prep_cnorm, dim3(1), dim3(256), 0, stream, hc, cn);
  hipLaunchKernelGGL(router_kernel, dim3(256, 2), dim3(512), 0, stream,
                     xh, xl, rwh, rwl, zf);
  hipLaunchKernelGGL(zero_cnt, dim3(1), dim3(64), 0, stream, cnt);
  hipLaunchKernelGGL(route_topk, dim3(1024), dim3(256), 0, stream,
                     zf, cn, temp, cnt, perm, pr);
  hipLaunchKernelGGL(main_sparse, dim3(36, 16), dim3(256), 0, stream,
                     xh, wh, bias, cnt, perm, pr, out);
}

// Round 5
// 485.157 us; speedup vs baseline: 1.4092x; 1.4092x over previous
//
#include <hip/hip_runtime.h>
#include <hip/hip_fp16.h>
#include <cstdint>
#include <cstddef>
#include <cmath>

// Problem constants
#define T_TOK 16384      // B*S tokens
#define DIN   2048
#define HIDN  256
#define NHEAD 16
#define HDIM  128
#define NKT   32         // DIN / 64
#define CAPH  4608       // per-head token capacity (mean 4096, sd ~55 -> 9 sigma)

typedef __attribute__((ext_vector_type(4))) float    f32x4;
typedef __attribute__((ext_vector_type(4))) int      i32x4;
typedef __attribute__((ext_vector_type(8))) _Float16 f16x8;
typedef __attribute__((ext_vector_type(4))) _Float16 f16x4;

// ---- workspace layout (bytes) ----
#define OFF_XH   ((size_t)0)
#define OFF_XL   ((size_t)67108864)
#define OFF_WH   ((size_t)134217728)
#define OFF_RWH  ((size_t)142606336)
#define OFF_RWL  ((size_t)143654912)
#define OFF_CN   ((size_t)144703488)
// routing scratch reuses the xl region (xl is dead after router_kernel):
#define OFF_GIDX (OFF_XL)                          // 16384*4 ints   = 262144 B
#define OFF_GPRB (OFF_XL + 262144)                 // 16384*4 floats = 262144 B
#define OFF_CNT  (OFF_XL + 524288)                 // 16 ints (pad to 1 KB)
#define OFF_PERM (OFF_XL + 525312)                 // 16*4608 ints  (token<<2 | slot)
#define OFF_PR   (OFF_PERM + (size_t)NHEAD * CAPH * 4)   // 16*4608 floats
// z scratch lives in d_out (16.7 MB of 33.5 MB); main_sparse fully overwrites d_out later.

__device__ __forceinline__ void gl_lds16(const void* g, void* l) {
  __builtin_amdgcn_global_load_lds(
      (const __attribute__((address_space(1))) unsigned int*)g,
      (__attribute__((address_space(3))) unsigned int*)l, 16, 0, 0);
}

// ---------------- prep: fp32 -> tiled fp16 (hi/lo split) ----------------
__global__ void prep_convert(const float* __restrict__ x,
                             const float* __restrict__ w,
                             const float* __restrict__ rw,
                             _Float16* __restrict__ xh, _Float16* __restrict__ xl,
                             _Float16* __restrict__ wh,
                             _Float16* __restrict__ rwh, _Float16* __restrict__ rwl) {
  size_t i = (size_t)blockIdx.x * 256 + threadIdx.x;
  if (i < 8388608) {                       // x: 16384 x 2048 (float4 units)
    const f32x4 v = ((const f32x4*)x)[i];
    size_t t = i >> 9;
    int r4 = (int)(i & 511);
    int kt = r4 >> 4;
    int k  = (r4 & 15) << 2;
    size_t o = (((size_t)kt * T_TOK + t) << 6) + k;
    _Float16 h0 = (_Float16)v.x, h1 = (_Float16)v.y,
             h2 = (_Float16)v.z, h3 = (_Float16)v.w;
    *(f16x4*)(xh + o) = (f16x4){h0, h1, h2, h3};
    _Float16 l0 = (_Float16)((v.x - (float)h0) * 4096.0f);
    _Float16 l1 = (_Float16)((v.y - (float)h1) * 4096.0f);
    _Float16 l2 = (_Float16)((v.z - (float)h2) * 4096.0f);
    _Float16 l3 = (_Float16)((v.w - (float)h3) * 4096.0f);
    *(f16x4*)(xl + o) = (f16x4){l0, l1, l2, l3};
  } else if (i < 9437184) {                // weight: 2048 x 2048, scaled x64
    size_t j = i - 8388608;
    const f32x4 v = ((const f32x4*)w)[j];
    size_t row = j >> 9;
    int r4 = (int)(j & 511);
    int kt = r4 >> 4;
    int k  = (r4 & 15) << 2;
    size_t o = (((size_t)kt * 2048 + row) << 6) + k;
    *(f16x4*)(wh + o) = (f16x4){(_Float16)(v.x * 64.0f), (_Float16)(v.y * 64.0f),
                                (_Float16)(v.z * 64.0f), (_Float16)(v.w * 64.0f)};
  } else if (i < 9568256) {                // router_w: 256 x 2048, hi/lo
    size_t j = i - 9437184;
    const f32x4 v = ((const f32x4*)rw)[j];
    size_t row = j >> 9;
    int r4 = (int)(j & 511);
    int kt = r4 >> 4;
    int k  = (r4 & 15) << 2;
    size_t o = (((size_t)kt * 256 + row) << 6) + k;
    _Float16 h0 = (_Float16)v.x, h1 = (_Float16)v.y,
             h2 = (_Float16)v.z, h3 = (_Float16)v.w;
    *(f16x4*)(rwh + o) = (f16x4){h0, h1, h2, h3};
    _Float16 l0 = (_Float16)((v.x - (float)h0) * 4096.0f);
    _Float16 l1 = (_Float16)((v.y - (float)h1) * 4096.0f);
    _Float16 l2 = (_Float16)((v.z - (float)h2) * 4096.0f);
    _Float16 l3 = (_Float16)((v.w - (float)h3) * 4096.0f);
    *(f16x4*)(rwl + o) = (f16x4){l0, l1, l2, l3};
  }
}

// ---------------- centroid normalize (fp64 norm, fp32 division like np) ----------------
__global__ void prep_cnorm(const float* __restrict__ c, float* __restrict__ cn) {
  int tid = threadIdx.x;              // 256 threads
  int h = tid >> 4, j = tid & 15;
  double s = 0.0;
  #pragma unroll
  for (int q = 0; q < 16; q++) {
    double v = (double)c[h * HIDN + j * 16 + q];
    s = fma(v, v, s);
  }
  s += __shfl_xor(s, 1, 64);
  s += __shfl_xor(s, 2, 64);
  s += __shfl_xor(s, 4, 64);
  s += __shfl_xor(s, 8, 64);
  float nf = (float)fmax(sqrt(s), 1e-12);
  #pragma unroll
  for (int q = 0; q < 16; q++)
    cn[h * HIDN + j * 16 + q] = c[h * HIDN + j * 16 + q] / nf;
}

// ---------------- router z-GEMM: N-split 128 cols, single staging phase, 2 barriers/kt ----
// Arithmetic chain per output element identical to R2/R3 (bit-frozen).
__launch_bounds__(512, 2)
__global__ void router_kernel(const _Float16* __restrict__ xh,
                              const _Float16* __restrict__ xl,
                              const _Float16* __restrict__ rwh,
                              const _Float16* __restrict__ rwl,
                              float* __restrict__ zf) {
  __shared__ struct {
    _Float16 Ah[64 * 64];    // 8 KB
    _Float16 Al[64 * 64];    // 8 KB
    _Float16 Bh[128 * 64];   // 16 KB
    _Float16 Bl[128 * 64];   // 16 KB
  } u;                       // 48 KB

  const int tid  = threadIdx.x;
  const int w    = tid >> 6;
  const int lane = tid & 63;
  const int lm   = lane & 15;
  const int quad = lane >> 4;
  const int wm   = w & 1;    // m-half (32 rows)
  const int wn   = w >> 1;   // n-quarter of 128 (32 cols)
  const int t0   = blockIdx.x * 64;
  const int nb   = blockIdx.y;          // 0/1: which 128-col half of HIDN

  double zacc[2][2][4];
  f32x4 accB[2][2];
  #pragma unroll
  for (int a = 0; a < 2; a++)
    #pragma unroll
    for (int b = 0; b < 2; b++) {
      accB[a][b] = (f32x4)0.0f;
      #pragma unroll
      for (int q = 0; q < 4; q++) zacc[a][b][q] = 0.0;
    }

  for (int kt = 0; kt < NKT; kt++) {
    if (kt) __syncthreads();
    {
      const char* ah_src = (const char*)(xh + (((size_t)kt * T_TOK + t0) << 6));
      const char* al_src = (const char*)(xl + (((size_t)kt * T_TOK + t0) << 6));
      const char* bh_src = (const char*)(rwh + (((size_t)kt * 256 + nb * 128) << 6));
      const char* bl_src = (const char*)(rwl + (((size_t)kt * 256 + nb * 128) << 6));
      gl_lds16(ah_src + w * 1024 + lane * 16, (char*)u.Ah + w * 1024);
      gl_lds16(al_src + w * 1024 + lane * 16, (char*)u.Al + w * 1024);
      #pragma unroll
      for (int c = 0; c < 2; c++) {
        gl_lds16(bh_src + (w * 2 + c) * 1024 + lane * 16, (char*)u.Bh + (w * 2 + c) * 1024);
        gl_lds16(bl_src + (w * 2 + c) * 1024 + lane * 16, (char*)u.Bl + (w * 2 + c) * 1024);
      }
    }
    __syncthreads();
    f32x4 accA[2][2];
    #pragma unroll
    for (int a = 0; a < 2; a++)
      #pragma unroll
      for (int b = 0; b < 2; b++) accA[a][b] = (f32x4)0.0f;
    // phase 1: accA += Ah*Bh ; accB += Al*Bh  (ks0 then ks1)
    #pragma unroll
    for (int ks = 0; ks < 2; ks++) {
      const int ko = ks * 32 + quad * 8;
      f16x8 ah[2], al[2], bh[2];
      #pragma unroll
      for (int fm = 0; fm < 2; fm++) {
        int r = wm * 32 + fm * 16 + lm;
        ah[fm] = *(const f16x8*)(u.Ah + r * 64 + ko);
        al[fm] = *(const f16x8*)(u.Al + r * 64 + ko);
      }
      #pragma unroll
      for (int fn = 0; fn < 2; fn++) {
        int r = wn * 32 + fn * 16 + lm;
        bh[fn] = *(const f16x8*)(u.Bh + r * 64 + ko);
      }
      #pragma unroll
      for (int fm = 0; fm < 2; fm++)
        #pragma unroll
        for (int fn = 0; fn < 2; fn++) {
          accA[fm][fn] = __builtin_amdgcn_mfma_f32_16x16x32_f16(ah[fm], bh[fn], accA[fm][fn], 0, 0, 0);
          accB[fm][fn] = __builtin_amdgcn_mfma_f32_16x16x32_f16(al[fm], bh[fn], accB[fm][fn], 0, 0, 0);
        }
    }
    // phase 2: accB += Ah*Bl  (ks0 then ks1) -- Bl already staged, no barrier
    #pragma unroll
    for (int ks = 0; ks < 2; ks++) {
      const int ko = ks * 32 + quad * 8;
      f16x8 ah[2], bl[2];
      #pragma unroll
      for (int fm = 0; fm < 2; fm++) {
        int r = wm * 32 + fm * 16 + lm;
        ah[fm] = *(const f16x8*)(u.Ah + r * 64 + ko);
      }
      #pragma unroll
      for (int fn = 0; fn < 2; fn++) {
        int r = wn * 32 + fn * 16 + lm;
        bl[fn] = *(const f16x8*)(u.Bl + r * 64 + ko);
      }
      #pragma unroll
      for (int fm = 0; fm < 2; fm++)
        #pragma unroll
        for (int fn = 0; fn < 2; fn++)
          accB[fm][fn] = __builtin_amdgcn_mfma_f32_16x16x32_f16(ah[fm], bl[fn], accB[fm][fn], 0, 0, 0);
    }
    // fp64 outer accumulation of this K-tile's hi*hi partial
    #pragma unroll
    for (int fm = 0; fm < 2; fm++)
      #pragma unroll
      for (int fn = 0; fn < 2; fn++)
        #pragma unroll
        for (int q = 0; q < 4; q++)
          zacc[fm][fn][q] += (double)accA[fm][fn][q];
  }

  // epilogue: identical arithmetic, direct global store
  #pragma unroll
  for (int fm = 0; fm < 2; fm++)
    #pragma unroll
    for (int fn = 0; fn < 2; fn++)
      #pragma unroll
      for (int i2 = 0; i2 < 4; i2++) {
        const int row = t0 + wm * 32 + fm * 16 + quad * 4 + i2;
        const int col = nb * 128 + wn * 32 + fn * 16 + lm;
        zf[(size_t)row * 256 + col] =
            (float)(zacc[fm][fn][i2] + (double)accB[fm][fn][i2] * (1.0 / 4096.0));
      }
}

// ---------------- routing: l2norm, logits, softmax, top-4 (bit-exact, NO atomics) -------
__launch_bounds__(256, 4)
__global__ void route_topk(const float* __restrict__ zf,
                           const float* __restrict__ cn,
                           const float* __restrict__ temp,
                           int* __restrict__ gidx,
                           float* __restrict__ gprb) {
  const int tid  = threadIdx.x;
  const int w    = tid >> 6;
  const int lane = tid & 63;
  const int lm   = lane & 15;
  const int quad = lane >> 4;
  const int t    = blockIdx.x * 16 + w * 4 + quad;

  const float* zrow = zf + (size_t)t * 256;
  double ssq = 0.0;
  #pragma unroll
  for (int c16 = 0; c16 < 16; c16++) {
    double zv = (double)zrow[c16 * 16 + lm];
    ssq = fma(zv, zv, ssq);
  }
  ssq += __shfl_xor(ssq, 1, 64);
  ssq += __shfl_xor(ssq, 2, 64);
  ssq += __shfl_xor(ssq, 4, 64);
  ssq += __shfl_xor(ssq, 8, 64);
  const float* crow = cn + lm * 256;
  double dot = 0.0;
  #pragma unroll 8
  for (int c = 0; c < 256; c++)
    dot = fma((double)zrow[c], (double)crow[c], dot);
  double nd = fmax(sqrt(ssq), 1e-12);
  float lgt = (float)(dot / nd) * 0.0625f * expf(temp[0]);

  float mx = lgt;
  mx = fmaxf(mx, __shfl_xor(mx, 1, 64));
  mx = fmaxf(mx, __shfl_xor(mx, 2, 64));
  mx = fmaxf(mx, __shfl_xor(mx, 4, 64));
  mx = fmaxf(mx, __shfl_xor(mx, 8, 64));
  float e = (float)exp((double)(lgt - mx));
  float s = e;
  s = s + __shfl_xor(s, 8, 64);
  s = s + __shfl_xor(s, 1, 64);
  s = s + __shfl_xor(s, 2, 64);
  s = s + __shfl_xor(s, 4, 64);
  float p = e / s;      // IEEE fp32 division

  // top-4: lexicographic max on (p, -h) == serial strict-> scan, lowest-index ties
  float pc = p;
  int bi[4]; float bp[4];
  #pragma unroll
  for (int k = 0; k < 4; k++) {
    float bv = pc; int bh = lm;
    #pragma unroll
    for (int m = 1; m < 16; m <<= 1) {
      float ov = __shfl_xor(bv, m, 64);
      int   oh = __shfl_xor(bh, m, 64);
      bool take = (ov > bv) || (ov == bv && oh < bh);
      bv = take ? ov : bv;
      bh = take ? oh : bh;
    }
    bi[k] = bh; bp[k] = bv;
    if (lm == bh) pc = -1.0f;
  }
  if (lm == 0) {
    *(i32x4*)(gidx + (size_t)t * 4) = (i32x4){bi[0], bi[1], bi[2], bi[3]};
    *(f32x4*)(gprb + (size_t)t * 4) = (f32x4){bp[0], bp[1], bp[2], bp[3]};
  }
}

// ---------------- bucket build: per-head token lists via ballot prefix (no atomics) -----
__launch_bounds__(256, 4)
__global__ void bucket_build(const int* __restrict__ gidx,
                             const float* __restrict__ gprb,
                             int* __restrict__ cnt,
                             int* __restrict__ perm,
                             float* __restrict__ pr) {
  const int h   = blockIdx.x;          // one block per head
  const int tid = threadIdx.x;
  const int w   = tid >> 6;
  const int lane = tid & 63;
  __shared__ int waveSum[4];
  __shared__ int baseS;
  if (tid == 0) baseS = 0;
  __syncthreads();

  for (int chunk = 0; chunk < T_TOK; chunk += 256) {
    const int t = chunk + tid;
    const i32x4 g = *(const i32x4*)(gidx + (size_t)t * 4);
    int k = -1;
    if      (g.x == h) k = 0;
    else if (g.y == h) k = 1;
    else if (g.z == h) k = 2;
    else if (g.w == h) k = 3;
    const bool flag = (k >= 0);
    const unsigned long long bal = __ballot(flag);
    const int wpre = __popcll(bal & ((1ull << lane) - 1ull));
    if (lane == 0) waveSum[w] = __popcll(bal);
    __syncthreads();
    int woff = 0;
    #pragma unroll
    for (int i = 0; i < 4; i++) if (i < w) woff += waveSum[i];
    const int btot = waveSum[0] + waveSum[1] + waveSum[2] + waveSum[3];
    const int pos = baseS + woff + wpre;
    if (flag && pos < CAPH) {
      const f32x4 p = *(const f32x4*)(gprb + (size_t)t * 4);
      const float pv = (k == 0) ? p.x : (k == 1) ? p.y : (k == 2) ? p.z : p.w;
      perm[h * CAPH + pos] = (t << 2) | k;
      pr[h * CAPH + pos]   = pv;
    }
    __syncthreads();
    if (tid == 0) baseS += btot;
    __syncthreads();
  }
  if (tid == 0) cnt[h] = min(baseS, CAPH);
}

// ---------------- sparse main GEMM: per-head gathered tokens, 4x fewer FLOPs ----------------
// MFMA chain per (token, head) output element identical to the dense R3 kernel (bit-frozen).
__launch_bounds__(256, 4)
__global__ void main_sparse(const _Float16* __restrict__ xh,
                            const _Float16* __restrict__ wh,
                            const float* __restrict__ bias,
                            const int* __restrict__ cnt,
                            const int* __restrict__ perm,
                            const float* __restrict__ pr,
                            float* __restrict__ out) {
  __shared__ _Float16 As[128 * 64];
  __shared__ _Float16 Bs[128 * 64];
  __shared__ int   tokS[128];
  __shared__ int   slotS[128];
  __shared__ float prbS[128];
  __shared__ int   vldS[128];

  const int tid  = threadIdx.x;
  const int w    = tid >> 6;
  const int lane = tid & 63;
  const int lm   = lane & 15;
  const int quad = lane >> 4;
  const int wm   = w & 1;
  const int wn   = w >> 1;
  const int h    = blockIdx.y;

  const int cnt_h = min(cnt[h], CAPH);
  const int base  = blockIdx.x * 128;
  if (base >= cnt_h) return;
  const int rows = min(128, cnt_h - base);

  if (tid < 128) {
    int idx = h * CAPH + base + (tid < rows ? tid : 0);
    int e = perm[idx];
    tokS[tid]  = e >> 2;
    slotS[tid] = e & 3;
    prbS[tid]  = pr[idx];
    vldS[tid]  = (tid < rows) ? 1 : 0;
  }
  __syncthreads();

  // per-lane gathered row tokens for the 4 A-staging calls
  int tokc[4];
  #pragma unroll
  for (int c = 0; c < 4; c++)
    tokc[c] = tokS[w * 32 + c * 8 + (lane >> 3)];

  f32x4 acc[4][4];
  #pragma unroll
  for (int a = 0; a < 4; a++)
    #pragma unroll
    for (int b = 0; b < 4; b++) acc[a][b] = (f32x4)0.0f;

  const char* xh_b = (const char*)xh;
  for (int kt = 0; kt < NKT; kt++) {
    if (kt) __syncthreads();
    const char* bsrc = (const char*)(wh + (((size_t)kt * 2048 + h * 128) << 6));
    #pragma unroll
    for (int c = 0; c < 4; c++) {
      // A: gather row tokc[c]; 8 lanes per 128B row
      gl_lds16(xh_b + (((size_t)kt * T_TOK + tokc[c]) << 7) + (lane & 7) * 16,
               (char*)As + (w * 4 + c) * 1024);
      gl_lds16(bsrc + (w * 4 + c) * 1024 + lane * 16, (char*)Bs + (w * 4 + c) * 1024);
    }
    __syncthreads();
    #pragma unroll
    for (int ks = 0; ks < 2; ks++) {
      const int ko = ks * 32 + quad * 8;
      f16x8 a[4], b[4];
      #pragma unroll
      for (int f = 0; f < 4; f++)
        a[f] = *(const f16x8*)(As + (wm * 64 + f * 16 + lm) * 64 + ko);
      #pragma unroll
      for (int f = 0; f < 4; f++)
        b[f] = *(const f16x8*)(Bs + (wn * 64 + f * 16 + lm) * 64 + ko);
      #pragma unroll
      for (int fm = 0; fm < 4; fm++)
        #pragma unroll
        for (int fn = 0; fn < 4; fn++)
          acc[fm][fn] = __builtin_amdgcn_mfma_f32_16x16x32_f16(a[fm], b[fn], acc[fm][fn], 0, 0, 0);
    }
  }

  float bias_v[4];
  #pragma unroll
  for (int fn = 0; fn < 4; fn++)
    bias_v[fn] = bias[h * 128 + wn * 64 + fn * 16 + lm];

  #pragma unroll
  for (int fm = 0; fm < 4; fm++) {
    const int rbase = wm * 64 + fm * 16 + quad * 4;
    #pragma unroll
    for (int i2 = 0; i2 < 4; i2++) {
      const int rr = rbase + i2;
      if (vldS[rr]) {
        const float sc = prbS[rr];
        const size_t obase = (size_t)tokS[rr] * 512 + (size_t)slotS[rr] * 128 + wn * 64;
        #pragma unroll
        for (int fn = 0; fn < 4; fn++)
          out[obase + fn * 16 + lm] = (acc[fm][fn][i2] * (1.0f / 64.0f) + bias_v[fn]) * sc;
      }
    }
  }
}

extern "C" void kernel_launch(void* const* d_in, const int* in_sizes, int n_in,
                              void* d_out, int out_size, void* d_ws, size_t ws_size,
                              hipStream_t stream) {
  const float* x    = (const float*)d_in[0];
  const float* rw   = (const float*)d_in[1];
  const float* hc   = (const float*)d_in[2];
  const float* temp = (const float*)d_in[3];
  const float* wt   = (const float*)d_in[4];
  const float* bias = (const float*)d_in[5];
  float* out = (float*)d_out;
  char* ws = (char*)d_ws;

  _Float16* xh   = (_Float16*)(ws + OFF_XH);
  _Float16* xl   = (_Float16*)(ws + OFF_XL);
  _Float16* wh   = (_Float16*)(ws + OFF_WH);
  _Float16* rwh  = (_Float16*)(ws + OFF_RWH);
  _Float16* rwl  = (_Float16*)(ws + OFF_RWL);
  float*    cn   = (float*)(ws + OFF_CN);
  int*      gidx = (int*)(ws + OFF_GIDX);   // aliases xl (dead after router)
  float*    gprb = (float*)(ws + OFF_GPRB);
  int*      cnt  = (int*)(ws + OFF_CNT);
  int*      perm = (int*)(ws + OFF_PERM);
  float*    pr   = (float*)(ws + OFF_PR);
  float*    zf   = out;   // 16.7 MB scratch inside d_out; fully overwritten by main_sparse

  hipLaunchKernelGGL(prep_convert, dim3(37376), dim3(256), 0, stream,
                     x, wt, rw, xh, xl, wh, rwh, rwl);
  hipLaunchKernelGGL(prep_cnorm, dim3(1), dim3(256), 0, stream, hc, cn);
  hipLaunchKernelGGL(router_kernel, dim3(256, 2), dim3(512), 0, stream,
                     xh, xl, rwh, rwl, zf);
  hipLaunchKernelGGL(route_topk, dim3(1024), dim3(256), 0, stream,
                     zf, cn, temp, gidx, gprb);
  hipLaunchKernelGGL(bucket_build, dim3(16), dim3(256), 0, stream,
                     gidx, gprb, cnt, perm, pr);
  hipLaunchKernelGGL(main_sparse, dim3(36, 16), dim3(256), 0, stream,
                     xh, wh, bias, cnt, perm, pr, out);
}